// Round 3
// baseline (174.411 us; speedup 1.0000x reference)
//
#include <hip/hip_runtime.h>

#define NB 8
#define NT 1024
#define NE 128
#define NH 8
#define NS 16

// Workspace layout (floats). Each of Q/K/V/Y is B*H*T*S = B*T*E = 1048576 floats (4 MB).
//   Q: [0, 1048576)          [b][h][t][d], scaled by 1/sqrt(E)
//   K: [1048576, 2097152)    [b][h][t][d]
//   V: [2097152, 3145728)    [b][h][t][d]
//   Y: [3145728, 4194304)    [b][t][e]  (attention output, pre-Wu)
//   vidx  (int): float offset 4194304, NB*NT ints
//   vcount(int): after vidx, NB ints
// Total ~16.03 MB of d_ws.
#define WS_Q 0
#define WS_K 1048576
#define WS_V 2097152
#define WS_Y 3145728
#define WS_VIDX 4194304

#define WT_PITCH 132  // multiple of 4 -> every row 16B-aligned for float4 LDS reads

static __device__ __forceinline__ void fma4(float4& acc, float s, const float4 v) {
  acc.x = fmaf(s, v.x, acc.x);
  acc.y = fmaf(s, v.y, acc.y);
  acc.z = fmaf(s, v.z, acc.z);
  acc.w = fmaf(s, v.w, acc.w);
}

// ---------------- Kernel A: fused QKV projection -------------------------
// grid = B*T/16 blocks, 256 threads. Each block handles 16 (b,t) rows.
__global__ __launch_bounds__(256) void qkv_kernel(
    const float* __restrict__ x, const float* __restrict__ Wq,
    const float* __restrict__ Wk, const float* __restrict__ Wv,
    float* __restrict__ Q, float* __restrict__ K, float* __restrict__ V) {
  __shared__ float xs[16 * 128];
  __shared__ float wq[16 * 17], wk[16 * 17], wv[16 * 17];  // scalar reads only
  const int tid = threadIdx.x;
  {
    int dd = tid >> 4, ss = tid & 15;
    wq[dd * 17 + ss] = Wq[tid];
    wk[dd * 17 + ss] = Wk[tid];
    wv[dd * 17 + ss] = Wv[tid];
  }
  const int r0 = blockIdx.x * 16;  // global row = b*NT + t
  const float4* xg = (const float4*)(x + (size_t)r0 * 128);
  float4* xs4 = (float4*)xs;
  xs4[tid] = xg[tid];
  xs4[tid + 256] = xg[tid + 256];
  __syncthreads();
  const int rh = tid >> 7;          // 0..1
  const int lane = tid & 127;
  const int h = lane >> 4, d = lane & 15;
  const float invs = 0.08838834764831845f;  // 1/sqrt(128): both q,k scales folded
  const float* wqr = wq + d * 17;
  const float* wkr = wk + d * 17;
  const float* wvr = wv + d * 17;
  for (int rr = rh; rr < 16; rr += 2) {
    const float* xr = xs + rr * 128 + h * 16;
    float aq = 0.f, ak = 0.f, av = 0.f;
#pragma unroll
    for (int s = 0; s < 16; s++) {
      float xv = xr[s];
      aq = fmaf(xv, wqr[s], aq);
      ak = fmaf(xv, wkr[s], ak);
      av = fmaf(xv, wvr[s], av);
    }
    int row = r0 + rr;
    int b = row >> 10, t = row & 1023;
    size_t o = ((size_t)(b * NH + h) * NT + t) * NS + d;
    Q[o] = aq * invs;
    K[o] = ak;
    V[o] = av;
  }
}

// ---------------- Kernel M: compact valid key indices per batch ----------
// grid = NB blocks, 64 threads (1 wave). Deterministic ordered compaction.
__global__ __launch_bounds__(64) void compact_kernel(
    const int* __restrict__ masks, int* __restrict__ vidx,
    int* __restrict__ vcount) {
  const int b = blockIdx.x, lane = threadIdx.x;
  int base = 0;
  for (int c = 0; c < NT; c += 64) {
    int t = c + lane;
    int v = masks[b * NT + t] != 0;
    unsigned long long bal = __ballot(v);
    int pos = base + __popcll(bal & ((1ull << lane) - 1ull));
    if (v) vidx[b * NT + pos] = t;
    base += __popcll(bal);
  }
  if (lane == 0) vcount[b] = base;
}

// ---------------- Kernel B: masked attention (one thread per query) ------
// grid = B*H*(T/256) = 256 blocks, 256 threads.
__global__ __launch_bounds__(256) void attn_kernel(
    const float* __restrict__ Q, const float* __restrict__ K,
    const float* __restrict__ V, const int* __restrict__ masks,
    const int* __restrict__ vidx, const int* __restrict__ vcount,
    float* __restrict__ Y) {
  __shared__ float Ks[128 * 16];  // 8 KB; rows are 16 floats -> b128 aligned
  __shared__ float Vs[128 * 16];  // 8 KB
  const int tid = threadIdx.x;
  const int bh = blockIdx.x >> 2;
  const int b = bh >> 3, h = bh & 7;
  const int t = ((blockIdx.x & 3) << 8) + tid;
  const int nv = vcount[b];
  const float4* qg = (const float4*)(Q + ((size_t)bh * NT + t) * NS);
  const float4 q0 = qg[0], q1 = qg[1], q2 = qg[2], q3 = qg[3];
  const int qm = masks[b * NT + t];
  float m = -1e30f, l = 0.f;
  float4 o0 = {0, 0, 0, 0}, o1 = {0, 0, 0, 0}, o2 = {0, 0, 0, 0},
         o3 = {0, 0, 0, 0};

  for (int k0 = 0; k0 < nv; k0 += 128) {
    __syncthreads();
    // stage 128 gathered K/V rows (zero-fill past nv so 0*pad stays finite)
    const int quad = tid & 3;
    const int jr = tid >> 2;  // 0..63
#pragma unroll
    for (int p = 0; p < 2; p++) {
      int row = jr + (p << 6);  // 0..127
      int j = k0 + row;
      float4 kv = {0, 0, 0, 0}, vv = {0, 0, 0, 0};
      if (j < nv) {
        int kk = vidx[b * NT + j];
        size_t base = ((size_t)bh * NT + kk) * NS + (quad << 2);
        kv = *(const float4*)(K + base);
        vv = *(const float4*)(V + base);
      }
      *(float4*)(Ks + row * 16 + (quad << 2)) = kv;
      *(float4*)(Vs + row * 16 + (quad << 2)) = vv;
    }
    __syncthreads();
    int jmax = nv - k0;
    if (jmax > 128) jmax = 128;
    for (int jj = 0; jj < jmax; jj += 4) {
      float s[4];
#pragma unroll
      for (int i = 0; i < 4; i++) {
        const float4* kr = (const float4*)(Ks + (jj + i) * 16);
        float4 a = kr[0], bb = kr[1], cc = kr[2], dd = kr[3];
        float s0 = (q0.x * a.x + q0.y * a.y) + (q0.z * a.z + q0.w * a.w);
        float s1 = (q1.x * bb.x + q1.y * bb.y) + (q1.z * bb.z + q1.w * bb.w);
        float s2 = (q2.x * cc.x + q2.y * cc.y) + (q2.z * cc.z + q2.w * cc.w);
        float s3 = (q3.x * dd.x + q3.y * dd.y) + (q3.z * dd.z + q3.w * dd.w);
        s[i] = (s0 + s1) + (s2 + s3);
      }
#pragma unroll
      for (int i = 0; i < 4; i++)
        if (jj + i >= jmax) s[i] = -1e30f;  // uniform, ~free
      float mb = fmaxf(fmaxf(s[0], s[1]), fmaxf(s[2], s[3]));
      if (mb > m) {  // rare (log-many times over the key loop)
        float alpha = __expf(m - mb);
        l *= alpha;
        o0.x *= alpha; o0.y *= alpha; o0.z *= alpha; o0.w *= alpha;
        o1.x *= alpha; o1.y *= alpha; o1.z *= alpha; o1.w *= alpha;
        o2.x *= alpha; o2.y *= alpha; o2.z *= alpha; o2.w *= alpha;
        o3.x *= alpha; o3.y *= alpha; o3.z *= alpha; o3.w *= alpha;
        m = mb;
      }
      float p0 = __expf(s[0] - m);
      float p1 = __expf(s[1] - m);
      float p2 = __expf(s[2] - m);
      float p3 = __expf(s[3] - m);
      l += (p0 + p1) + (p2 + p3);
      float pv[4] = {p0, p1, p2, p3};
#pragma unroll
      for (int i = 0; i < 4; i++) {
        const float4* vr = (const float4*)(Vs + (jj + i) * 16);
        fma4(o0, pv[i], vr[0]);
        fma4(o1, pv[i], vr[1]);
        fma4(o2, pv[i], vr[2]);
        fma4(o3, pv[i], vr[3]);
      }
    }
  }
  // masked query or no valid keys -> exact zero row (matches reference)
  const float inv = (qm != 0 && l > 0.f) ? (1.0f / l) : 0.f;
  float4* yo = (float4*)(Y + ((size_t)b * NT + t) * NE + h * NS);
  o0.x *= inv; o0.y *= inv; o0.z *= inv; o0.w *= inv;
  o1.x *= inv; o1.y *= inv; o1.z *= inv; o1.w *= inv;
  o2.x *= inv; o2.y *= inv; o2.z *= inv; o2.w *= inv;
  o3.x *= inv; o3.y *= inv; o3.z *= inv; o3.w *= inv;
  yo[0] = o0; yo[1] = o1; yo[2] = o2; yo[3] = o3;
}

// ---------------- Kernel C: out = Y @ Wu^T + bu --------------------------
// grid = B*T/32 = 256 blocks, 256 threads. 32 rows per block.
__global__ __launch_bounds__(256) void proj_kernel(
    const float* __restrict__ Y, const float* __restrict__ Wu,
    const float* __restrict__ bu, float* __restrict__ out) {
  __shared__ float Wt[64 * WT_PITCH];  // transposed Wu chunk; pitch%4==0 -> aligned b128
  __shared__ float Yt[32 * 128];
  const int tid = threadIdx.x;
  const int r0 = blockIdx.x * 32;
  // stage Y tile (32 rows x 128)
  const float4* yg = (const float4*)(Y + (size_t)r0 * 128);
  float4* yt4 = (float4*)Yt;
#pragma unroll
  for (int p = 0; p < 4; p++) yt4[tid + p * 256] = yg[tid + p * 256];
  const int c0 = (tid & 31) << 2;  // 4 output cols
  const int rg = tid >> 5;         // 8 groups x 4 rows
  float4 acc0 = *(const float4*)(bu + c0);
  float4 acc1 = acc0, acc2 = acc0, acc3 = acc0;
  for (int e0 = 0; e0 < 128; e0 += 64) {
    __syncthreads();  // covers Yt staging (first iter) + Wt reuse
#pragma unroll
    for (int p = 0; p < 8; p++) {
      int idx = tid + p * 256;        // 2048 float4s of this e-chunk
      int c = idx >> 4;
      int es = (idx & 15) << 2;
      float4 w = *(const float4*)(Wu + c * 128 + e0 + es);
      Wt[(es + 0) * WT_PITCH + c] = w.x;
      Wt[(es + 1) * WT_PITCH + c] = w.y;
      Wt[(es + 2) * WT_PITCH + c] = w.z;
      Wt[(es + 3) * WT_PITCH + c] = w.w;
    }
    __syncthreads();
    const float* y0 = Yt + (rg * 4 + 0) * 128 + e0;
    const float* y1 = Yt + (rg * 4 + 1) * 128 + e0;
    const float* y2 = Yt + (rg * 4 + 2) * 128 + e0;
    const float* y3 = Yt + (rg * 4 + 3) * 128 + e0;
#pragma unroll 4
    for (int e = 0; e < 64; e += 4) {
      float4 w0 = *(const float4*)(Wt + (e + 0) * WT_PITCH + c0);
      float4 w1 = *(const float4*)(Wt + (e + 1) * WT_PITCH + c0);
      float4 w2 = *(const float4*)(Wt + (e + 2) * WT_PITCH + c0);
      float4 w3 = *(const float4*)(Wt + (e + 3) * WT_PITCH + c0);
      float4 ya = *(const float4*)(y0 + e);
      float4 yb = *(const float4*)(y1 + e);
      float4 yc = *(const float4*)(y2 + e);
      float4 yd = *(const float4*)(y3 + e);
      fma4(acc0, ya.x, w0); fma4(acc0, ya.y, w1); fma4(acc0, ya.z, w2); fma4(acc0, ya.w, w3);
      fma4(acc1, yb.x, w0); fma4(acc1, yb.y, w1); fma4(acc1, yb.z, w2); fma4(acc1, yb.w, w3);
      fma4(acc2, yc.x, w0); fma4(acc2, yc.y, w1); fma4(acc2, yc.z, w2); fma4(acc2, yc.w, w3);
      fma4(acc3, yd.x, w0); fma4(acc3, yd.y, w1); fma4(acc3, yd.z, w2); fma4(acc3, yd.w, w3);
    }
  }
  *(float4*)(out + (size_t)(r0 + rg * 4 + 0) * 128 + c0) = acc0;
  *(float4*)(out + (size_t)(r0 + rg * 4 + 1) * 128 + c0) = acc1;
  *(float4*)(out + (size_t)(r0 + rg * 4 + 2) * 128 + c0) = acc2;
  *(float4*)(out + (size_t)(r0 + rg * 4 + 3) * 128 + c0) = acc3;
}

extern "C" void kernel_launch(void* const* d_in, const int* in_sizes, int n_in,
                              void* d_out, int out_size, void* d_ws,
                              size_t ws_size, hipStream_t stream) {
  const float* x = (const float*)d_in[0];
  const int* masks = (const int*)d_in[1];
  const float* Wq = (const float*)d_in[2];
  const float* Wk = (const float*)d_in[3];
  const float* Wv = (const float*)d_in[4];
  const float* Wu = (const float*)d_in[5];
  const float* bu = (const float*)d_in[6];
  float* out = (float*)d_out;

  float* ws = (float*)d_ws;
  float* Q = ws + WS_Q;
  float* K = ws + WS_K;
  float* V = ws + WS_V;
  float* Y = ws + WS_Y;
  int* vidx = (int*)(ws + WS_VIDX);
  int* vcount = vidx + NB * NT;

  qkv_kernel<<<NB * NT / 16, 256, 0, stream>>>(x, Wq, Wk, Wv, Q, K, V);
  compact_kernel<<<NB, 64, 0, stream>>>(masks, vidx, vcount);
  attn_kernel<<<NB * NH * (NT / 256), 256, 0, stream>>>(Q, K, V, masks, vidx,
                                                        vcount, Y);
  proj_kernel<<<NB * NT / 32, 256, 0, stream>>>(Y, Wu, bu, out);
}

// Round 4
// 144.720 us; speedup vs baseline: 1.2052x; 1.2052x over previous
//
#include <hip/hip_runtime.h>

#define NB 8
#define NT 1024
#define NE 128
#define NH 8
#define NS 16

// Workspace layout (floats). Each of Q/K/V/Y is B*H*T*S = B*T*E = 1048576 floats (4 MB).
#define WS_Q 0
#define WS_K 1048576
#define WS_V 2097152
#define WS_Y 3145728
#define WS_VIDX 4194304

#define WT_PITCH 132  // multiple of 4 -> every row 16B-aligned for float4 LDS reads

static __device__ __forceinline__ void fma4(float4& acc, float s, const float4 v) {
  acc.x = fmaf(s, v.x, acc.x);
  acc.y = fmaf(s, v.y, acc.y);
  acc.z = fmaf(s, v.z, acc.z);
  acc.w = fmaf(s, v.w, acc.w);
}

// ---------------- Kernel A: fused QKV projection -------------------------
__global__ __launch_bounds__(256) void qkv_kernel(
    const float* __restrict__ x, const float* __restrict__ Wq,
    const float* __restrict__ Wk, const float* __restrict__ Wv,
    float* __restrict__ Q, float* __restrict__ K, float* __restrict__ V) {
  __shared__ float xs[16 * 128];
  __shared__ float wq[16 * 17], wk[16 * 17], wv[16 * 17];
  const int tid = threadIdx.x;
  {
    int dd = tid >> 4, ss = tid & 15;
    wq[dd * 17 + ss] = Wq[tid];
    wk[dd * 17 + ss] = Wk[tid];
    wv[dd * 17 + ss] = Wv[tid];
  }
  const int r0 = blockIdx.x * 16;  // global row = b*NT + t
  const float4* xg = (const float4*)(x + (size_t)r0 * 128);
  float4* xs4 = (float4*)xs;
  xs4[tid] = xg[tid];
  xs4[tid + 256] = xg[tid + 256];
  __syncthreads();
  const int rh = tid >> 7;
  const int lane = tid & 127;
  const int h = lane >> 4, d = lane & 15;
  const float invs = 0.08838834764831845f;  // 1/sqrt(128)
  const float* wqr = wq + d * 17;
  const float* wkr = wk + d * 17;
  const float* wvr = wv + d * 17;
  for (int rr = rh; rr < 16; rr += 2) {
    const float* xr = xs + rr * 128 + h * 16;
    float aq = 0.f, ak = 0.f, av = 0.f;
#pragma unroll
    for (int s = 0; s < 16; s++) {
      float xv = xr[s];
      aq = fmaf(xv, wqr[s], aq);
      ak = fmaf(xv, wkr[s], ak);
      av = fmaf(xv, wvr[s], av);
    }
    int row = r0 + rr;
    int b = row >> 10, t = row & 1023;
    size_t o = ((size_t)(b * NH + h) * NT + t) * NS + d;
    Q[o] = aq * invs;
    K[o] = ak;
    V[o] = av;
  }
}

// ---------------- Kernel M: compact valid key indices per batch ----------
__global__ __launch_bounds__(64) void compact_kernel(
    const int* __restrict__ masks, int* __restrict__ vidx,
    int* __restrict__ vcount) {
  const int b = blockIdx.x, lane = threadIdx.x;
  int base = 0;
  for (int c = 0; c < NT; c += 64) {
    int t = c + lane;
    int v = masks[b * NT + t] != 0;
    unsigned long long bal = __ballot(v);
    int pos = base + __popcll(bal & ((1ull << lane) - 1ull));
    if (v) vidx[b * NT + pos] = t;
    base += __popcll(bal);
  }
  if (lane == 0) vcount[b] = base;
}

// ---------------- Kernel B: split-K masked attention ---------------------
// grid = B*H*(T/64) = 1024 blocks, 256 threads.
// Block = 64 queries x 4 key-splits. Wave s handles tile rows r == s (mod 4).
// In-block combine of partials via LDS (om overlays Ks/Vs: both 16 KB).
__global__ __launch_bounds__(256) void attn_kernel(
    const float* __restrict__ Q, const float* __restrict__ K,
    const float* __restrict__ V, const int* __restrict__ masks,
    const int* __restrict__ vidx, const int* __restrict__ vcount,
    float* __restrict__ Y) {
  __shared__ float KsVs[4096];      // Ks=[0,2048), Vs=[2048,4096); later om[4][64][16]
  __shared__ float ml[4 * 64 * 2];  // (m,l) per (split, queryLane)
  float* Ks = KsVs;
  float* Vs = KsVs + 2048;
  const int tid = threadIdx.x;
  const int lane = tid & 63;    // query lane
  const int split = tid >> 6;   // 0..3
  const int bh = blockIdx.x >> 4;
  const int b = bh >> 3, h = bh & 7;
  const int t = ((blockIdx.x & 15) << 6) + lane;
  const int nv = vcount[b];
  const float4* qg = (const float4*)(Q + ((size_t)bh * NT + t) * NS);
  const float4 q0 = qg[0], q1 = qg[1], q2 = qg[2], q3 = qg[3];
  const int qm = masks[b * NT + t];
  float m = -1e30f, l = 0.f;
  float4 o0 = {0, 0, 0, 0}, o1 = {0, 0, 0, 0}, o2 = {0, 0, 0, 0},
         o3 = {0, 0, 0, 0};

  for (int k0 = 0; k0 < nv; k0 += 128) {
    __syncthreads();
    // stage 128 gathered K/V rows cooperatively (zero-fill past nv)
    const int quad = tid & 3;
    const int jr = tid >> 2;  // 0..63
#pragma unroll
    for (int p = 0; p < 2; p++) {
      int row = jr + (p << 6);
      int j = k0 + row;
      float4 kv = {0, 0, 0, 0}, vv = {0, 0, 0, 0};
      if (j < nv) {
        int kk = vidx[b * NT + j];
        size_t base = ((size_t)bh * NT + kk) * NS + (quad << 2);
        kv = *(const float4*)(K + base);
        vv = *(const float4*)(V + base);
      }
      *(float4*)(Ks + row * 16 + (quad << 2)) = kv;
      *(float4*)(Vs + row * 16 + (quad << 2)) = vv;
    }
    __syncthreads();
    int jmax = nv - k0;
    if (jmax > 128) jmax = 128;
    // wave `split` processes rows split, split+4, ..., in groups of 4 rows
    for (int g = 0; g < 8; g++) {
      const int rbase = split + (g << 4);
      if (rbase >= jmax) break;  // wave-uniform
      float s[4];
#pragma unroll
      for (int i = 0; i < 4; i++) {
        const float4* kr = (const float4*)(Ks + (rbase + (i << 2)) * 16);
        float4 a = kr[0], bb = kr[1], cc = kr[2], dd = kr[3];
        float s0 = (q0.x * a.x + q0.y * a.y) + (q0.z * a.z + q0.w * a.w);
        float s1 = (q1.x * bb.x + q1.y * bb.y) + (q1.z * bb.z + q1.w * bb.w);
        float s2 = (q2.x * cc.x + q2.y * cc.y) + (q2.z * cc.z + q2.w * cc.w);
        float s3 = (q3.x * dd.x + q3.y * dd.y) + (q3.z * dd.z + q3.w * dd.w);
        s[i] = (s0 + s1) + (s2 + s3);
      }
#pragma unroll
      for (int i = 0; i < 4; i++)
        if (rbase + (i << 2) >= jmax) s[i] = -1e30f;
      float mb = fmaxf(fmaxf(s[0], s[1]), fmaxf(s[2], s[3]));
      if (mb > m) {  // rare
        float alpha = __expf(m - mb);
        l *= alpha;
        o0.x *= alpha; o0.y *= alpha; o0.z *= alpha; o0.w *= alpha;
        o1.x *= alpha; o1.y *= alpha; o1.z *= alpha; o1.w *= alpha;
        o2.x *= alpha; o2.y *= alpha; o2.z *= alpha; o2.w *= alpha;
        o3.x *= alpha; o3.y *= alpha; o3.z *= alpha; o3.w *= alpha;
        m = mb;
      }
      float p0 = __expf(s[0] - m);
      float p1 = __expf(s[1] - m);
      float p2 = __expf(s[2] - m);
      float p3 = __expf(s[3] - m);
      l += (p0 + p1) + (p2 + p3);
      float pv[4] = {p0, p1, p2, p3};
#pragma unroll
      for (int i = 0; i < 4; i++) {
        const float4* vr = (const float4*)(Vs + (rbase + (i << 2)) * 16);
        fma4(o0, pv[i], vr[0]);
        fma4(o1, pv[i], vr[1]);
        fma4(o2, pv[i], vr[2]);
        fma4(o3, pv[i], vr[3]);
      }
    }
  }
  // ---- in-block split combine ----
  ml[((split << 6) | lane) * 2 + 0] = m;
  ml[((split << 6) | lane) * 2 + 1] = l;
  __syncthreads();  // all compute done; ml visible; Ks/Vs now dead
  float m0 = ml[lane * 2 + 0], l0 = ml[lane * 2 + 1];
  float m1 = ml[(64 + lane) * 2 + 0], l1 = ml[(64 + lane) * 2 + 1];
  float m2 = ml[(128 + lane) * 2 + 0], l2 = ml[(128 + lane) * 2 + 1];
  float m3 = ml[(192 + lane) * 2 + 0], l3 = ml[(192 + lane) * 2 + 1];
  float M = fmaxf(fmaxf(m0, m1), fmaxf(m2, m3));
  float L = l0 * __expf(m0 - M) + l1 * __expf(m1 - M) + l2 * __expf(m2 - M) +
            l3 * __expf(m3 - M);
  float alpha = __expf(m - M);  // own rescale
  o0.x *= alpha; o0.y *= alpha; o0.z *= alpha; o0.w *= alpha;
  o1.x *= alpha; o1.y *= alpha; o1.z *= alpha; o1.w *= alpha;
  o2.x *= alpha; o2.y *= alpha; o2.z *= alpha; o2.w *= alpha;
  o3.x *= alpha; o3.y *= alpha; o3.z *= alpha; o3.w *= alpha;
  float* om = KsVs + ((split << 6) | lane) * 16;
  *(float4*)(om + 0) = o0;
  *(float4*)(om + 4) = o1;
  *(float4*)(om + 8) = o2;
  *(float4*)(om + 12) = o3;
  __syncthreads();
  if (split == 0) {
    float4 y0 = {0, 0, 0, 0}, y1 = {0, 0, 0, 0}, y2 = {0, 0, 0, 0},
           y3 = {0, 0, 0, 0};
#pragma unroll
    for (int s = 0; s < 4; s++) {
      const float* p = KsVs + ((s << 6) | lane) * 16;
      float4 a = *(const float4*)(p + 0);
      float4 bq = *(const float4*)(p + 4);
      float4 c = *(const float4*)(p + 8);
      float4 d = *(const float4*)(p + 12);
      y0.x += a.x; y0.y += a.y; y0.z += a.z; y0.w += a.w;
      y1.x += bq.x; y1.y += bq.y; y1.z += bq.z; y1.w += bq.w;
      y2.x += c.x; y2.y += c.y; y2.z += c.z; y2.w += c.w;
      y3.x += d.x; y3.y += d.y; y3.z += d.z; y3.w += d.w;
    }
    const float inv = (qm != 0 && L > 0.f) ? (1.0f / L) : 0.f;
    y0.x *= inv; y0.y *= inv; y0.z *= inv; y0.w *= inv;
    y1.x *= inv; y1.y *= inv; y1.z *= inv; y1.w *= inv;
    y2.x *= inv; y2.y *= inv; y2.z *= inv; y2.w *= inv;
    y3.x *= inv; y3.y *= inv; y3.z *= inv; y3.w *= inv;
    float4* yo = (float4*)(Y + ((size_t)b * NT + t) * NE + h * NS);
    yo[0] = y0; yo[1] = y1; yo[2] = y2; yo[3] = y3;
  }
}

// ---------------- Kernel C: out = Y @ Wu^T + bu --------------------------
__global__ __launch_bounds__(256) void proj_kernel(
    const float* __restrict__ Y, const float* __restrict__ Wu,
    const float* __restrict__ bu, float* __restrict__ out) {
  __shared__ float Wt[64 * WT_PITCH];
  __shared__ float Yt[32 * 128];
  const int tid = threadIdx.x;
  const int r0 = blockIdx.x * 32;
  const float4* yg = (const float4*)(Y + (size_t)r0 * 128);
  float4* yt4 = (float4*)Yt;
#pragma unroll
  for (int p = 0; p < 4; p++) yt4[tid + p * 256] = yg[tid + p * 256];
  const int c0 = (tid & 31) << 2;
  const int rg = tid >> 5;
  float4 acc0 = *(const float4*)(bu + c0);
  float4 acc1 = acc0, acc2 = acc0, acc3 = acc0;
  for (int e0 = 0; e0 < 128; e0 += 64) {
    __syncthreads();
#pragma unroll
    for (int p = 0; p < 8; p++) {
      int idx = tid + p * 256;
      int c = idx >> 4;
      int es = (idx & 15) << 2;
      float4 w = *(const float4*)(Wu + c * 128 + e0 + es);
      Wt[(es + 0) * WT_PITCH + c] = w.x;
      Wt[(es + 1) * WT_PITCH + c] = w.y;
      Wt[(es + 2) * WT_PITCH + c] = w.z;
      Wt[(es + 3) * WT_PITCH + c] = w.w;
    }
    __syncthreads();
    const float* y0 = Yt + (rg * 4 + 0) * 128 + e0;
    const float* y1 = Yt + (rg * 4 + 1) * 128 + e0;
    const float* y2 = Yt + (rg * 4 + 2) * 128 + e0;
    const float* y3 = Yt + (rg * 4 + 3) * 128 + e0;
#pragma unroll 4
    for (int e = 0; e < 64; e += 4) {
      float4 w0 = *(const float4*)(Wt + (e + 0) * WT_PITCH + c0);
      float4 w1 = *(const float4*)(Wt + (e + 1) * WT_PITCH + c0);
      float4 w2 = *(const float4*)(Wt + (e + 2) * WT_PITCH + c0);
      float4 w3 = *(const float4*)(Wt + (e + 3) * WT_PITCH + c0);
      float4 ya = *(const float4*)(y0 + e);
      float4 yb = *(const float4*)(y1 + e);
      float4 yc = *(const float4*)(y2 + e);
      float4 yd = *(const float4*)(y3 + e);
      fma4(acc0, ya.x, w0); fma4(acc0, ya.y, w1); fma4(acc0, ya.z, w2); fma4(acc0, ya.w, w3);
      fma4(acc1, yb.x, w0); fma4(acc1, yb.y, w1); fma4(acc1, yb.z, w2); fma4(acc1, yb.w, w3);
      fma4(acc2, yc.x, w0); fma4(acc2, yc.y, w1); fma4(acc2, yc.z, w2); fma4(acc2, yc.w, w3);
      fma4(acc3, yd.x, w0); fma4(acc3, yd.y, w1); fma4(acc3, yd.z, w2); fma4(acc3, yd.w, w3);
    }
  }
  *(float4*)(out + (size_t)(r0 + rg * 4 + 0) * 128 + c0) = acc0;
  *(float4*)(out + (size_t)(r0 + rg * 4 + 1) * 128 + c0) = acc1;
  *(float4*)(out + (size_t)(r0 + rg * 4 + 2) * 128 + c0) = acc2;
  *(float4*)(out + (size_t)(r0 + rg * 4 + 3) * 128 + c0) = acc3;
}

extern "C" void kernel_launch(void* const* d_in, const int* in_sizes, int n_in,
                              void* d_out, int out_size, void* d_ws,
                              size_t ws_size, hipStream_t stream) {
  const float* x = (const float*)d_in[0];
  const int* masks = (const int*)d_in[1];
  const float* Wq = (const float*)d_in[2];
  const float* Wk = (const float*)d_in[3];
  const float* Wv = (const float*)d_in[4];
  const float* Wu = (const float*)d_in[5];
  const float* bu = (const float*)d_in[6];
  float* out = (float*)d_out;

  float* ws = (float*)d_ws;
  float* Q = ws + WS_Q;
  float* K = ws + WS_K;
  float* V = ws + WS_V;
  float* Y = ws + WS_Y;
  int* vidx = (int*)(ws + WS_VIDX);
  int* vcount = vidx + NB * NT;

  qkv_kernel<<<NB * NT / 16, 256, 0, stream>>>(x, Wq, Wk, Wv, Q, K, V);
  compact_kernel<<<NB, 64, 0, stream>>>(masks, vidx, vcount);
  attn_kernel<<<NB * NH * (NT / 64), 256, 0, stream>>>(Q, K, V, masks, vidx,
                                                       vcount, Y);
  proj_kernel<<<NB * NT / 32, 256, 0, stream>>>(Y, Wu, bu, out);
}

// Round 5
// 140.539 us; speedup vs baseline: 1.2410x; 1.0297x over previous
//
#include <hip/hip_runtime.h>

#define NB 8
#define NT 1024
#define NE 128
#define NH 8
#define NS 16

// Workspace layout (floats). Each of Q/K/V/Y is B*H*T*S = B*T*E = 1048576 floats (4 MB).
#define WS_Q 0
#define WS_K 1048576
#define WS_V 2097152
#define WS_Y 3145728
#define WS_VIDX 4194304

#define WT_PITCH 132  // multiple of 4 -> every row 16B-aligned for float4 LDS reads

static __device__ __forceinline__ void fma4(float4& acc, float s, const float4 v) {
  acc.x = fmaf(s, v.x, acc.x);
  acc.y = fmaf(s, v.y, acc.y);
  acc.z = fmaf(s, v.z, acc.z);
  acc.w = fmaf(s, v.w, acc.w);
}

static __device__ __forceinline__ float dot16(const float4 x0, const float4 x1,
                                              const float4 x2, const float4 x3,
                                              const float4 w0, const float4 w1,
                                              const float4 w2, const float4 w3) {
  float s0 = (x0.x * w0.x + x0.y * w0.y) + (x0.z * w0.z + x0.w * w0.w);
  float s1 = (x1.x * w1.x + x1.y * w1.y) + (x1.z * w1.z + x1.w * w1.w);
  float s2 = (x2.x * w2.x + x2.y * w2.y) + (x2.z * w2.z + x2.w * w2.w);
  float s3 = (x3.x * w3.x + x3.y * w3.y) + (x3.z * w3.z + x3.w * w3.w);
  return (s0 + s1) + (s2 + s3);
}

// ---------------- Kernel A: fused QKV projection + mask compaction -------
// blocks [0,1024): qkv. block -> (h = blk&7, rowgroup = blk>>3 of 64 rows).
// Thread: d = tid&15, rows = base + (tid>>4)*4 .. +3. W rows in registers.
// blocks [1024,1032): per-batch mask compaction (wave 0 only).
__global__ __launch_bounds__(256) void qkv_kernel(
    const float* __restrict__ x, const int* __restrict__ masks,
    const float* __restrict__ Wq, const float* __restrict__ Wk,
    const float* __restrict__ Wv, float* __restrict__ Q, float* __restrict__ K,
    float* __restrict__ V, int* __restrict__ vidx, int* __restrict__ vcount) {
  if (blockIdx.x >= 1024) {
    const int b = blockIdx.x - 1024;
    const int lane = threadIdx.x;
    if (lane < 64) {
      int base = 0;
      for (int c = 0; c < NT; c += 64) {
        int t = c + lane;
        int v = masks[b * NT + t] != 0;
        unsigned long long bal = __ballot(v);
        int pos = base + __popcll(bal & ((1ull << lane) - 1ull));
        if (v) vidx[b * NT + pos] = t;
        base += __popcll(bal);
      }
      if (lane == 0) vcount[b] = base;
    }
    return;
  }
  const int tid = threadIdx.x;
  const int h = blockIdx.x & 7;
  const int rg = blockIdx.x >> 3;  // 0..127
  const int b = rg >> 4;
  const int base = rg << 6;              // global row base (b*NT + t)
  const int d = tid & 15;
  const int r = base + ((tid >> 4) << 2);  // first of this thread's 4 rows
  const float4* wq4 = (const float4*)(Wq + d * 16);
  const float4 wq0 = wq4[0], wq1 = wq4[1], wq2 = wq4[2], wq3 = wq4[3];
  const float4* wk4 = (const float4*)(Wk + d * 16);
  const float4 wk0 = wk4[0], wk1 = wk4[1], wk2 = wk4[2], wk3 = wk4[3];
  const float4* wv4 = (const float4*)(Wv + d * 16);
  const float4 wv0 = wv4[0], wv1 = wv4[1], wv2 = wv4[2], wv3 = wv4[3];
  const float invs = 0.08838834764831845f;  // 1/sqrt(128)
#pragma unroll
  for (int i = 0; i < 4; i++) {
    const int row = r + i;
    const float4* xp = (const float4*)(x + (size_t)row * 128 + h * 16);
    const float4 x0 = xp[0], x1 = xp[1], x2 = xp[2], x3 = xp[3];
    float aq = dot16(x0, x1, x2, x3, wq0, wq1, wq2, wq3);
    float ak = dot16(x0, x1, x2, x3, wk0, wk1, wk2, wk3);
    float av = dot16(x0, x1, x2, x3, wv0, wv1, wv2, wv3);
    const int t = row & 1023;
    size_t o = ((size_t)(b * NH + h) * NT + t) * NS + d;
    Q[o] = aq * invs;
    K[o] = ak;
    V[o] = av;
  }
}

// ---------------- Kernel B: split-K masked attention, 2 queries/thread ---
// grid = B*H*(T/128) = 512 blocks, 256 threads.
// Block = 128 queries x 4 key-splits. Wave s handles tile rows r == s (mod 4).
// Each thread owns 2 queries (tA = base+lane, tB = tA+64): every K/V LDS read
// feeds 2 dots -> halves the LDS-issue bound that limited round 4.
__global__ __launch_bounds__(256) void attn_kernel(
    const float* __restrict__ Q, const float* __restrict__ K,
    const float* __restrict__ V, const int* __restrict__ masks,
    const int* __restrict__ vidx, const int* __restrict__ vcount,
    float* __restrict__ Y) {
  __shared__ __align__(16) float Ks[2048];
  __shared__ __align__(16) float Vs[2048];
  __shared__ __align__(16) float om[2][4][64][20];  // raw o partials, pitch 20
  __shared__ float ml[2][4][64][2];                 // (m,l) per (qg,split,lane)
  const int tid = threadIdx.x;
  const int lane = tid & 63;
  const int split = tid >> 6;  // 0..3
  const int bh = blockIdx.x >> 3;
  const int b = bh >> 3, h = bh & 7;
  const int tbase = (blockIdx.x & 7) << 7;
  const int tA = tbase + lane;
  const int nv = vcount[b];
  const float4* qga = (const float4*)(Q + ((size_t)bh * NT + tA) * NS);
  const float4 qa0 = qga[0], qa1 = qga[1], qa2 = qga[2], qa3 = qga[3];
  const float4* qgb = (const float4*)(Q + ((size_t)bh * NT + tA + 64) * NS);
  const float4 qb0 = qgb[0], qb1 = qgb[1], qb2 = qgb[2], qb3 = qgb[3];
  float mA = -1e30f, lA = 0.f, mB = -1e30f, lB = 0.f;
  float4 oa0 = {0, 0, 0, 0}, oa1 = {0, 0, 0, 0}, oa2 = {0, 0, 0, 0},
         oa3 = {0, 0, 0, 0};
  float4 ob0 = {0, 0, 0, 0}, ob1 = {0, 0, 0, 0}, ob2 = {0, 0, 0, 0},
         ob3 = {0, 0, 0, 0};

  for (int k0 = 0; k0 < nv; k0 += 128) {
    __syncthreads();
    // stage 128 gathered K/V rows cooperatively (zero-fill past nv)
    const int quad = tid & 3;
    const int jr = tid >> 2;  // 0..63
#pragma unroll
    for (int p = 0; p < 2; p++) {
      int row = jr + (p << 6);
      int j = k0 + row;
      float4 kv = {0, 0, 0, 0}, vv = {0, 0, 0, 0};
      if (j < nv) {
        int kk = vidx[b * NT + j];
        size_t bse = ((size_t)bh * NT + kk) * NS + (quad << 2);
        kv = *(const float4*)(K + bse);
        vv = *(const float4*)(V + bse);
      }
      *(float4*)(Ks + row * 16 + (quad << 2)) = kv;
      *(float4*)(Vs + row * 16 + (quad << 2)) = vv;
    }
    __syncthreads();
    int jmax = nv - k0;
    if (jmax > 128) jmax = 128;
    for (int g = 0; g < 8; g++) {
      const int rbase = split + (g << 4);
      if (rbase >= jmax) break;  // wave-uniform
      float sA[4], sB[4];
#pragma unroll
      for (int i = 0; i < 4; i++) {
        const float4* kr = (const float4*)(Ks + (rbase + (i << 2)) * 16);
        float4 k0v = kr[0], k1v = kr[1], k2v = kr[2], k3v = kr[3];
        sA[i] = dot16(qa0, qa1, qa2, qa3, k0v, k1v, k2v, k3v);
        sB[i] = dot16(qb0, qb1, qb2, qb3, k0v, k1v, k2v, k3v);
      }
#pragma unroll
      for (int i = 0; i < 4; i++)
        if (rbase + (i << 2) >= jmax) { sA[i] = -1e30f; sB[i] = -1e30f; }
      // online update, query A
      float mbA = fmaxf(fmaxf(sA[0], sA[1]), fmaxf(sA[2], sA[3]));
      if (mbA > mA) {
        float al = __expf(mA - mbA);
        lA *= al;
        oa0.x *= al; oa0.y *= al; oa0.z *= al; oa0.w *= al;
        oa1.x *= al; oa1.y *= al; oa1.z *= al; oa1.w *= al;
        oa2.x *= al; oa2.y *= al; oa2.z *= al; oa2.w *= al;
        oa3.x *= al; oa3.y *= al; oa3.z *= al; oa3.w *= al;
        mA = mbA;
      }
      float pA[4];
      pA[0] = __expf(sA[0] - mA); pA[1] = __expf(sA[1] - mA);
      pA[2] = __expf(sA[2] - mA); pA[3] = __expf(sA[3] - mA);
      lA += (pA[0] + pA[1]) + (pA[2] + pA[3]);
      // online update, query B
      float mbB = fmaxf(fmaxf(sB[0], sB[1]), fmaxf(sB[2], sB[3]));
      if (mbB > mB) {
        float al = __expf(mB - mbB);
        lB *= al;
        ob0.x *= al; ob0.y *= al; ob0.z *= al; ob0.w *= al;
        ob1.x *= al; ob1.y *= al; ob1.z *= al; ob1.w *= al;
        ob2.x *= al; ob2.y *= al; ob2.z *= al; ob2.w *= al;
        ob3.x *= al; ob3.y *= al; ob3.z *= al; ob3.w *= al;
        mB = mbB;
      }
      float pB[4];
      pB[0] = __expf(sB[0] - mB); pB[1] = __expf(sB[1] - mB);
      pB[2] = __expf(sB[2] - mB); pB[3] = __expf(sB[3] - mB);
      lB += (pB[0] + pB[1]) + (pB[2] + pB[3]);
#pragma unroll
      for (int i = 0; i < 4; i++) {
        const float4* vr = (const float4*)(Vs + (rbase + (i << 2)) * 16);
        float4 v0 = vr[0], v1 = vr[1], v2 = vr[2], v3 = vr[3];
        fma4(oa0, pA[i], v0); fma4(oa1, pA[i], v1);
        fma4(oa2, pA[i], v2); fma4(oa3, pA[i], v3);
        fma4(ob0, pB[i], v0); fma4(ob1, pB[i], v1);
        fma4(ob2, pB[i], v2); fma4(ob3, pB[i], v3);
      }
    }
  }
  // ---- write raw partials; one sync; waves 0/1 combine ----
  ml[0][split][lane][0] = mA; ml[0][split][lane][1] = lA;
  ml[1][split][lane][0] = mB; ml[1][split][lane][1] = lB;
  {
    float* pa = &om[0][split][lane][0];
    *(float4*)(pa + 0) = oa0; *(float4*)(pa + 4) = oa1;
    *(float4*)(pa + 8) = oa2; *(float4*)(pa + 12) = oa3;
    float* pb = &om[1][split][lane][0];
    *(float4*)(pb + 0) = ob0; *(float4*)(pb + 4) = ob1;
    *(float4*)(pb + 8) = ob2; *(float4*)(pb + 12) = ob3;
  }
  __syncthreads();
  if (split < 2) {
    const int qg = split;
    const int tq = tbase + (qg << 6) + lane;
    float m0 = ml[qg][0][lane][0], l0 = ml[qg][0][lane][1];
    float m1 = ml[qg][1][lane][0], l1 = ml[qg][1][lane][1];
    float m2 = ml[qg][2][lane][0], l2 = ml[qg][2][lane][1];
    float m3 = ml[qg][3][lane][0], l3 = ml[qg][3][lane][1];
    float M = fmaxf(fmaxf(m0, m1), fmaxf(m2, m3));
    float f0 = __expf(m0 - M), f1 = __expf(m1 - M), f2 = __expf(m2 - M),
          f3 = __expf(m3 - M);
    float L = f0 * l0 + f1 * l1 + f2 * l2 + f3 * l3;
    float4 y0 = {0, 0, 0, 0}, y1 = {0, 0, 0, 0}, y2 = {0, 0, 0, 0},
           y3 = {0, 0, 0, 0};
    float fs[4] = {f0, f1, f2, f3};
#pragma unroll
    for (int s = 0; s < 4; s++) {
      const float* p = &om[qg][s][lane][0];
      fma4(y0, fs[s], *(const float4*)(p + 0));
      fma4(y1, fs[s], *(const float4*)(p + 4));
      fma4(y2, fs[s], *(const float4*)(p + 8));
      fma4(y3, fs[s], *(const float4*)(p + 12));
    }
    const int qm = masks[b * NT + tq];
    const float inv = (qm != 0 && L > 0.f) ? (1.0f / L) : 0.f;
    y0.x *= inv; y0.y *= inv; y0.z *= inv; y0.w *= inv;
    y1.x *= inv; y1.y *= inv; y1.z *= inv; y1.w *= inv;
    y2.x *= inv; y2.y *= inv; y2.z *= inv; y2.w *= inv;
    y3.x *= inv; y3.y *= inv; y3.z *= inv; y3.w *= inv;
    float4* yo = (float4*)(Y + ((size_t)b * NT + tq) * NE + h * NS);
    yo[0] = y0; yo[1] = y1; yo[2] = y2; yo[3] = y3;
  }
}

// ---------------- Kernel C: out = Y @ Wu^T + bu --------------------------
// grid = B*T/16 = 512 blocks (2 blocks/CU), 256 threads.
// 16 rows/block; threads: c0 = 4 cols, rg = 4 rowgroups x 4 rows, eh = e-half.
// 2-way e-split within block; partials combined via LDS (Wt reused).
__global__ __launch_bounds__(256) void proj_kernel(
    const float* __restrict__ Y, const float* __restrict__ Wu,
    const float* __restrict__ bu, float* __restrict__ out) {
  __shared__ __align__(16) float Wt[64 * WT_PITCH];  // 33792 B
  __shared__ __align__(16) float Yt[16 * 128];       // 8192 B
  const int tid = threadIdx.x;
  const int r0 = blockIdx.x * 16;
  const float4* yg = (const float4*)(Y + (size_t)r0 * 128);
  float4* yt4 = (float4*)Yt;
  yt4[tid] = yg[tid];
  yt4[tid + 256] = yg[tid + 256];
  const int c0 = (tid & 31) << 2;
  const int rg = (tid >> 5) & 3;
  const int eh = tid >> 7;  // 0 or 1
  float4 acc0 = {0, 0, 0, 0}, acc1 = {0, 0, 0, 0}, acc2 = {0, 0, 0, 0},
         acc3 = {0, 0, 0, 0};
  for (int e0 = 0; e0 < 128; e0 += 64) {
    __syncthreads();  // guards Yt staging (iter 0) and Wt reuse (iter 1)
#pragma unroll
    for (int p = 0; p < 8; p++) {
      int idx = tid + p * 256;
      int c = idx >> 4;
      int es = (idx & 15) << 2;
      float4 w = *(const float4*)(Wu + c * 128 + e0 + es);
      Wt[(es + 0) * WT_PITCH + c] = w.x;
      Wt[(es + 1) * WT_PITCH + c] = w.y;
      Wt[(es + 2) * WT_PITCH + c] = w.z;
      Wt[(es + 3) * WT_PITCH + c] = w.w;
    }
    __syncthreads();
    const int eb = eh << 5;  // this thread's e-half within the 64-chunk
    const float* y0 = Yt + (rg * 4 + 0) * 128 + e0 + eb;
    const float* y1 = Yt + (rg * 4 + 1) * 128 + e0 + eb;
    const float* y2 = Yt + (rg * 4 + 2) * 128 + e0 + eb;
    const float* y3 = Yt + (rg * 4 + 3) * 128 + e0 + eb;
#pragma unroll 4
    for (int e = 0; e < 32; e += 4) {
      const float* wb = Wt + (eb + e) * WT_PITCH + c0;
      float4 w0 = *(const float4*)(wb + 0 * WT_PITCH);
      float4 w1 = *(const float4*)(wb + 1 * WT_PITCH);
      float4 w2 = *(const float4*)(wb + 2 * WT_PITCH);
      float4 w3 = *(const float4*)(wb + 3 * WT_PITCH);
      float4 ya = *(const float4*)(y0 + e);
      float4 yb = *(const float4*)(y1 + e);
      float4 yc = *(const float4*)(y2 + e);
      float4 yd = *(const float4*)(y3 + e);
      fma4(acc0, ya.x, w0); fma4(acc0, ya.y, w1); fma4(acc0, ya.z, w2); fma4(acc0, ya.w, w3);
      fma4(acc1, yb.x, w0); fma4(acc1, yb.y, w1); fma4(acc1, yb.z, w2); fma4(acc1, yb.w, w3);
      fma4(acc2, yc.x, w0); fma4(acc2, yc.y, w1); fma4(acc2, yc.z, w2); fma4(acc2, yc.w, w3);
      fma4(acc3, yd.x, w0); fma4(acc3, yd.y, w1); fma4(acc3, yd.z, w2); fma4(acc3, yd.w, w3);
    }
  }
  // combine e-halves through LDS (Wt dead; pitch 20 to spread banks)
  __syncthreads();
  if (eh == 1) {
    float* p = Wt + (tid & 127) * 20;
    *(float4*)(p + 0) = acc0; *(float4*)(p + 4) = acc1;
    *(float4*)(p + 8) = acc2; *(float4*)(p + 12) = acc3;
  }
  __syncthreads();
  if (eh == 0) {
    const float* p = Wt + tid * 20;
    float4 b4 = *(const float4*)(bu + c0);
    float4 q0 = *(const float4*)(p + 0);
    float4 q1 = *(const float4*)(p + 4);
    float4 q2 = *(const float4*)(p + 8);
    float4 q3 = *(const float4*)(p + 12);
    acc0.x += q0.x + b4.x; acc0.y += q0.y + b4.y; acc0.z += q0.z + b4.z; acc0.w += q0.w + b4.w;
    acc1.x += q1.x + b4.x; acc1.y += q1.y + b4.y; acc1.z += q1.z + b4.z; acc1.w += q1.w + b4.w;
    acc2.x += q2.x + b4.x; acc2.y += q2.y + b4.y; acc2.z += q2.z + b4.z; acc2.w += q2.w + b4.w;
    acc3.x += q3.x + b4.x; acc3.y += q3.y + b4.y; acc3.z += q3.z + b4.z; acc3.w += q3.w + b4.w;
    *(float4*)(out + (size_t)(r0 + rg * 4 + 0) * 128 + c0) = acc0;
    *(float4*)(out + (size_t)(r0 + rg * 4 + 1) * 128 + c0) = acc1;
    *(float4*)(out + (size_t)(r0 + rg * 4 + 2) * 128 + c0) = acc2;
    *(float4*)(out + (size_t)(r0 + rg * 4 + 3) * 128 + c0) = acc3;
  }
}

extern "C" void kernel_launch(void* const* d_in, const int* in_sizes, int n_in,
                              void* d_out, int out_size, void* d_ws,
                              size_t ws_size, hipStream_t stream) {
  const float* x = (const float*)d_in[0];
  const int* masks = (const int*)d_in[1];
  const float* Wq = (const float*)d_in[2];
  const float* Wk = (const float*)d_in[3];
  const float* Wv = (const float*)d_in[4];
  const float* Wu = (const float*)d_in[5];
  const float* bu = (const float*)d_in[6];
  float* out = (float*)d_out;

  float* ws = (float*)d_ws;
  float* Q = ws + WS_Q;
  float* K = ws + WS_K;
  float* V = ws + WS_V;
  float* Y = ws + WS_Y;
  int* vidx = (int*)(ws + WS_VIDX);
  int* vcount = vidx + NB * NT;

  qkv_kernel<<<1024 + NB, 256, 0, stream>>>(x, masks, Wq, Wk, Wv, Q, K, V,
                                            vidx, vcount);
  attn_kernel<<<NB * NH * (NT / 128), 256, 0, stream>>>(Q, K, V, masks, vidx,
                                                        vcount, Y);
  proj_kernel<<<NB * NT / 16, 256, 0, stream>>>(Y, Wu, bu, out);
}